// Round 12
// baseline (420.277 us; speedup 1.0000x reference)
//
#include <hip/hip_runtime.h>
#include <hip/hip_fp16.h>

// Problem constants (fixed by the reference)
#define NN 50000      // nodes
#define EE 800000     // edges
#define FF 64         // F_IN = F_OUT
#define PP 8          // periods
#define NPAD 50048    // padded rows (multiple of 128, >= max GEMM tile row)
#define ELLW 64       // ELL slots per node (in-deg ~ Poisson(16); P(>64) ~ 1e-13)
#define NB_BUILD 1024 // build blocks (grid-stride): ~4 waves/CU, xpose co-runs
#define NB_XPOSE 12500 // NN/4
#define NB_WPACK 96   // 24576/256 Wfrag-pack blocks

typedef _Float16 half8 __attribute__((ext_vector_type(8)));
typedef float floatx4 __attribute__((ext_vector_type(4)));

static constexpr size_t al512(size_t x) { return (x + 511) & ~size_t(511); }
static constexpr size_t OFF_DEG  = 0;                                  // float[NN]
static constexpr size_t OFF_CNT  = al512(OFF_DEG  + (size_t)NN*4);     // int[NN]
static constexpr size_t OFF_END0 = al512(OFF_CNT  + (size_t)NN*4);     // end of zeroed region
static constexpr size_t OFF_ELL  = OFF_END0;                           // int2[NN*ELLW]
static constexpr size_t OFF_BIAS = al512(OFF_ELL  + (size_t)NN*ELLW*8);// float[192]
static constexpr size_t OFF_WC2  = al512(OFF_BIAS + 192*4);            // float[64]
static constexpr size_t OFF_WFRG = al512(OFF_WC2  + 64*4);             // half[24576]
static constexpr size_t OFF_XB   = al512(OFF_WFRG + (size_t)24576*2);  // half[NPAD*512]

// ---- K1: fused build + xpose + weight-prep (block-specialized) -------------
// Build: 1024 grid-stride blocks, 1 edge/thread/iter (R11 lesson: unroll x2
// regressed — atomic batching hurts at ANY occupancy; reverted). Xpose and
// weight-prep ranges co-run and hide partially under the atomic drain.
__global__ void k_bx(const int* __restrict__ src, const int* __restrict__ dst,
                     const float* __restrict__ ew,
                     float* __restrict__ deg, int* __restrict__ cnt,
                     int2* __restrict__ ell,
                     const float* __restrict__ X, _Float16* __restrict__ XB,
                     const float* __restrict__ Wx0, const float* __restrict__ Wx1,
                     const float* __restrict__ bx, const float* __restrict__ bh,
                     const float* __restrict__ wc, const float* __restrict__ bg,
                     _Float16* __restrict__ Wfrag, float* __restrict__ biasv,
                     float* __restrict__ wc2) {
    __shared__ _Float16 tile[4][512];
    int b = blockIdx.x;
    if (b < NB_BUILD) {
        const int stride = NB_BUILD * 256;
#pragma unroll 1
        for (int e = b * 256 + threadIdx.x; e < EE; e += stride) {
            int s = src[e], d = dst[e];
            float w = ew[e];
            atomicAdd(deg + s, w);              // fire-and-forget
            int pos = atomicAdd(cnt + d, 1);    // slot claim
            if (pos < ELLW) {
                int2 pr; pr.x = s; pr.y = __float_as_int(w);
                ell[(size_t)d * ELLW + pos] = pr;
            }
        }
    } else if (b < NB_BUILD + NB_XPOSE) {
        int wid = threadIdx.x >> 6, lane = threadIdx.x & 63;
        int n = (b - NB_BUILD) * 4 + wid;       // NN = 12500*4: no tail
        const float4* xp = (const float4*)(X + (size_t)n * 512 + lane * 8);
        float4 a = xp[0], c = xp[1];
        float v[8] = {a.x, a.y, a.z, a.w, c.x, c.y, c.z, c.w};
#pragma unroll
        for (int p = 0; p < PP; ++p)            // [p][f] layout, f = lane
            tile[wid][p * 64 + lane] = (_Float16)v[p];
        half8 vv = *(const half8*)&tile[wid][lane * 8];
        *(half8*)(XB + (size_t)n * 512 + lane * 8) = vv;
    } else if (b < NB_BUILD + NB_XPOSE + NB_WPACK) {
        // Wfrag pack: Wfrag[((ks*12+ct)*64+lane)*8+j] =
        //   W[k = ks*32+(lane>>4)*8+j][c = ct*16+(lane&15)]
        const int gmap[3] = {0, 2, 3};
        int t = (b - NB_BUILD - NB_XPOSE) * 256 + threadIdx.x;  // [0,24576)
        int j8 = t & 7;
        int lane = (t >> 3) & 63;
        int rem = t >> 9;           // [0,48)
        int ct = rem % 12;
        int ks = rem / 12;
        int k = ks * 32 + (lane >> 4) * 8 + j8;
        int gp = ct >> 2;
        int g = gmap[gp];
        int j64 = (ct & 3) * 16 + (lane & 15);
        float val = (k < 64) ? Wx0[((size_t)g * 64 + k) * 64 + j64]
                             : Wx1[((size_t)g * 64 + (k - 64)) * 64 + j64];
        Wfrag[t] = (_Float16)val;
    } else {
        // bias + wc2 (single block)
        const int gmap[3] = {0, 2, 3};
        int t = threadIdx.x;
        if (t < 192) {
            int gp = t / 64, j = t % 64;
            int g = gmap[gp];
            biasv[t] = bx[g * 64 + j] + bh[g * 64 + j] + bg[g * 64 + j];
        } else {
            int j = t - 192;                    // [0,64)
            wc2[j] = wc[2 * 64 + j];
        }
    }
}

__device__ __forceinline__ float fast_rcp(float x) { return __builtin_amdgcn_rcpf(x); }
__device__ __forceinline__ float sigmoidf_fast(float x) {
    return fast_rcp(1.f + __expf(-x));          // v_exp + v_rcp, no slow division
}
__device__ __forceinline__ float tanhf_fast(float x) {
    return 1.f - 2.f * fast_rcp(1.f + __expf(2.f * x));
}

// ---- K2: FUSED SpMM + MFMA GEMM + LSTM epilogue ----------------------------
// R12: eliminates the TB round-trip (spmm wrote 51 MB to HBM/L2, gemm re-read
// it; ~102 MB + one launch gap). Block = 32 rows x 128 thr (2 waves).
// Phase 1: wave w gathers rows [n0+w*16, +16) from ELL (readlane->SGPR
//   descriptors, 16 half8 row-gathers in flight) and writes the T-tile to
//   LDS with XOR swizzle col8 ^= row&7 (else fragment reads are a 16-way
//   bank conflict: lane stride 1024B).
// Phase 2: register-resident-B gemm (R9 structure); t-fragments from LDS.
__global__ __launch_bounds__(128) void k_sg(const _Float16* __restrict__ XB,
                                            const int* __restrict__ cnt,
                                            const float* __restrict__ deg,
                                            const int2* __restrict__ ell,
                                            const _Float16* __restrict__ Wfrag,
                                            const float* __restrict__ biasv,
                                            const float* __restrict__ wc2,
                                            float* __restrict__ out) {
    __shared__ _Float16 Tl[32][512];            // 32 KB T-tile
    const int tid = threadIdx.x;
    const int w = tid >> 6;                     // wave id 0/1
    const int lane = tid & 63;
    const int n0 = blockIdx.x * 32;

    // ---- Phase 1: gather 16 rows per wave into LDS ----
#pragma unroll 1
    for (int r = 0; r < 16; ++r) {
        const int lr = w * 16 + r;              // local row
        const int n = n0 + lr;
        float acc[8] = {0.f, 0.f, 0.f, 0.f, 0.f, 0.f, 0.f, 0.f};
        float dn = 0.f;
        if (n < NN) {
            int cn = min(cnt[n], ELLW);
            float dgn = deg[n];
            dn = dgn > 0.f ? rsqrtf(fmaxf(dgn, 1e-12f)) : 0.f;
            if (cn > 0) {
                const int2* __restrict__ row = ell + (size_t)n * ELLW;
                int2 ed = row[min(lane, cn - 1)];
                float dgs = deg[ed.x];
                float dsr = dgs > 0.f ? rsqrtf(fmaxf(dgs, 1e-12f)) : 0.f;
                float wl = (lane < cn) ? dsr * __int_as_float(ed.y) : 0.f;
                int wli = __float_as_int(wl);
                for (int base = 0; base < cn; base += 16) {
                    half8 rg[16];
                    float wk[16];
#pragma unroll
                    for (int u = 0; u < 16; ++u) {
                        int srck = __builtin_amdgcn_readlane(ed.x, base + u); // SGPR
                        wk[u] = __int_as_float(__builtin_amdgcn_readlane(wli, base + u));
                        rg[u] = *((const half8*)(XB + (size_t)srck * 512) + lane);
                    }
#pragma unroll
                    for (int u = 0; u < 16; ++u) {
#pragma unroll
                        for (int j = 0; j < 8; ++j) acc[j] += wk[u] * (float)rg[u][j];
                    }
                }
            }
        }
        half8 st;
#pragma unroll
        for (int j = 0; j < 8; ++j) st[j] = (_Float16)(-dn * acc[j]);
        ((half8*)&Tl[lr][0])[lane ^ (lr & 7)] = st;   // swizzled store
    }
    __syncthreads();

    // ---- Phase 2: GEMM + LSTM epilogue (B register-resident) ----
    const half8* __restrict__ Wg8 = (const half8*)Wfrag;
    const int jj = lane & 15, quad = lane >> 4;

    half8 Bf[2][3][4];                          // [c4local][gate i/c/o][ks]
#pragma unroll
    for (int c4l = 0; c4l < 2; ++c4l)
#pragma unroll
        for (int gp = 0; gp < 3; ++gp)
#pragma unroll
            for (int ks = 0; ks < 4; ++ks)
                Bf[c4l][gp][ks] = Wg8[(ks * 12 + gp * 4 + (w * 2 + c4l)) * 64 + lane];

    float bi[2], bc[2], bo[2], wcv[2];
#pragma unroll
    for (int c4l = 0; c4l < 2; ++c4l) {
        int j = (w * 2 + c4l) * 16 + jj;
        bi[c4l] = biasv[j];
        bc[c4l] = biasv[64 + j];
        bo[c4l] = biasv[128 + j];
        wcv[c4l] = wc2[j];
    }

    const _Float16* __restrict__ x0 = XB + (size_t)(n0 + jj) * 512;
    const _Float16* __restrict__ x1 = XB + (size_t)(n0 + 16 + jj) * 512;
    const int sw0 = jj & 7;                     // swizzle key rows jj and 16+jj

    floatx4 outacc[2][2];
#pragma unroll
    for (int r = 0; r < 2; ++r)
#pragma unroll
        for (int c4l = 0; c4l < 2; ++c4l) outacc[r][c4l] = (floatx4){0.f, 0.f, 0.f, 0.f};

#pragma unroll 1
    for (int p = 0; p < PP; ++p) {
        const int o = p * 64 + quad * 8;
        const int c8 = p * 8 + quad;            // col8 of the fragment
        half8 a00 = *(const half8*)(x0 + o);
        half8 a01 = *(const half8*)(x0 + o + 32);
        half8 a02 = ((const half8*)&Tl[jj][0])[c8 ^ sw0];
        half8 a03 = ((const half8*)&Tl[jj][0])[(c8 + 4) ^ sw0];
        half8 a10 = *(const half8*)(x1 + o);
        half8 a11 = *(const half8*)(x1 + o + 32);
        half8 a12 = ((const half8*)&Tl[16 + jj][0])[c8 ^ sw0];
        half8 a13 = ((const half8*)&Tl[16 + jj][0])[(c8 + 4) ^ sw0];
#pragma unroll
        for (int c4l = 0; c4l < 2; ++c4l) {
            floatx4 ai0 = {0.f,0.f,0.f,0.f}, ac0 = {0.f,0.f,0.f,0.f}, ao0 = {0.f,0.f,0.f,0.f};
            floatx4 ai1 = {0.f,0.f,0.f,0.f}, ac1 = {0.f,0.f,0.f,0.f}, ao1 = {0.f,0.f,0.f,0.f};
#pragma unroll
            for (int ks = 0; ks < 4; ++ks) {
                half8 a0 = (ks == 0) ? a00 : (ks == 1) ? a01 : (ks == 2) ? a02 : a03;
                half8 a1 = (ks == 0) ? a10 : (ks == 1) ? a11 : (ks == 2) ? a12 : a13;
                ai0 = __builtin_amdgcn_mfma_f32_16x16x32_f16(a0, Bf[c4l][0][ks], ai0, 0, 0, 0);
                ai1 = __builtin_amdgcn_mfma_f32_16x16x32_f16(a1, Bf[c4l][0][ks], ai1, 0, 0, 0);
                ac0 = __builtin_amdgcn_mfma_f32_16x16x32_f16(a0, Bf[c4l][1][ks], ac0, 0, 0, 0);
                ac1 = __builtin_amdgcn_mfma_f32_16x16x32_f16(a1, Bf[c4l][1][ks], ac1, 0, 0, 0);
                ao0 = __builtin_amdgcn_mfma_f32_16x16x32_f16(a0, Bf[c4l][2][ks], ao0, 0, 0, 0);
                ao1 = __builtin_amdgcn_mfma_f32_16x16x32_f16(a1, Bf[c4l][2][ks], ao1, 0, 0, 0);
            }
            // fused epilogue: I=sig(ai); T=tanh(ac); Cn=I*T; O=sig(ao+wc2*Cn)
#pragma unroll
            for (int rr = 0; rr < 4; ++rr) {
                float I0 = sigmoidf_fast(ai0[rr] + bi[c4l]);
                float T0 = tanhf_fast(ac0[rr] + bc[c4l]);
                float Cn0 = I0 * T0;
                float O0 = sigmoidf_fast(ao0[rr] + bo[c4l] + wcv[c4l] * Cn0);
                outacc[0][c4l][rr] += O0 * tanhf_fast(Cn0);
                float I1 = sigmoidf_fast(ai1[rr] + bi[c4l]);
                float T1 = tanhf_fast(ac1[rr] + bc[c4l]);
                float Cn1 = I1 * T1;
                float O1 = sigmoidf_fast(ao1[rr] + bo[c4l] + wcv[c4l] * Cn1);
                outacc[1][c4l][rr] += O1 * tanhf_fast(Cn1);
            }
        }
    }
    // store: row n = n0 + r*16 + quad*4 + rr, col = (w*2+c4l)*16 + jj
#pragma unroll
    for (int r = 0; r < 2; ++r)
#pragma unroll
        for (int c4l = 0; c4l < 2; ++c4l)
#pragma unroll
            for (int rr = 0; rr < 4; ++rr) {
                int n = n0 + r * 16 + quad * 4 + rr;
                if (n < NN) out[(size_t)n * 64 + (w * 2 + c4l) * 16 + jj] = outacc[r][c4l][rr];
            }
}

extern "C" void kernel_launch(void* const* d_in, const int* in_sizes, int n_in,
                              void* d_out, int out_size, void* d_ws, size_t ws_size,
                              hipStream_t stream) {
    const float* X   = (const float*)d_in[0];
    const int*   ei  = (const int*)d_in[1];
    const float* ew  = (const float*)d_in[2];
    const float* Wx0 = (const float*)d_in[3];
    const float* Wx1 = (const float*)d_in[4];
    const float* bx  = (const float*)d_in[5];
    // d_in[6], d_in[7] (Wh0, Wh1) are dead: H=0
    const float* bh  = (const float*)d_in[8];
    const float* wc  = (const float*)d_in[9];
    const float* bg  = (const float*)d_in[10];
    float* out = (float*)d_out;

    const int* src = ei;
    const int* dst = ei + EE;

    char* ws = (char*)d_ws;
    float* deg     = (float*)(ws + OFF_DEG);
    int*   cnt     = (int*)(ws + OFF_CNT);
    int2*  ell     = (int2*)(ws + OFF_ELL);
    float* biasv   = (float*)(ws + OFF_BIAS);
    float* wc2     = (float*)(ws + OFF_WC2);
    _Float16* Wfrag = (_Float16*)(ws + OFF_WFRG);
    _Float16* XB    = (_Float16*)(ws + OFF_XB);

    // zero deg + cnt (contiguous region at front of ws)
    hipMemsetAsync(ws, 0, OFF_END0, stream);

    // fused: build + xpose + Wfrag pack + bias/wc2 (block-specialized)
    k_bx<<<NB_BUILD + NB_XPOSE + NB_WPACK + 1, 256, 0, stream>>>(
        src, dst, ew, deg, cnt, ell, X, XB,
        Wx0, Wx1, bx, bh, wc, bg, Wfrag, biasv, wc2);
    // fused SpMM + GEMM + epilogue
    k_sg<<<NPAD / 32, 128, 0, stream>>>(XB, cnt, deg, ell, Wfrag, biasv, wc2, out);
}

// Round 13
// 408.082 us; speedup vs baseline: 1.0299x; 1.0299x over previous
//
#include <hip/hip_runtime.h>
#include <hip/hip_fp16.h>

// Problem constants (fixed by the reference)
#define NN 50000      // nodes
#define EE 800000     // edges
#define FF 64         // F_IN = F_OUT
#define PP 8          // periods
#define NPAD 50048    // padded rows (multiple of 128, >= max GEMM tile row)
#define ELLW 64       // ELL slots per node (in-deg ~ Poisson(16); P(>64) ~ 1e-13)
#define NB_BUILD 1024 // build blocks (grid-stride): ~4 waves/CU, xpose co-runs
#define NB_XPOSE 12500 // NN/4
#define NB_WPACK 96   // 24576/256 Wfrag-pack blocks

typedef _Float16 half8 __attribute__((ext_vector_type(8)));
typedef float floatx4 __attribute__((ext_vector_type(4)));

static constexpr size_t al512(size_t x) { return (x + 511) & ~size_t(511); }
static constexpr size_t OFF_DEG  = 0;                                  // float[NN]
static constexpr size_t OFF_CNT  = al512(OFF_DEG  + (size_t)NN*4);     // int[NN]
static constexpr size_t OFF_END0 = al512(OFF_CNT  + (size_t)NN*4);     // end of zeroed region
static constexpr size_t OFF_ELL  = OFF_END0;                           // int2[NN*ELLW]
static constexpr size_t OFF_BIAS = al512(OFF_ELL  + (size_t)NN*ELLW*8);// float[192]
static constexpr size_t OFF_WC2  = al512(OFF_BIAS + 192*4);            // float[64]
static constexpr size_t OFF_WFRG = al512(OFF_WC2  + 64*4);             // half[24576]
static constexpr size_t OFF_XB   = al512(OFF_WFRG + (size_t)24576*2);  // half[NPAD*512]

// ---- K1: fused build + xpose + weight-prep (block-specialized) -------------
// Build: 1024 grid-stride blocks, 1 edge/thread/iter (R11: batching hurts at
// any occupancy). Xpose and weight-prep ranges co-run under the atomic drain.
__global__ void k_bx(const int* __restrict__ src, const int* __restrict__ dst,
                     const float* __restrict__ ew,
                     float* __restrict__ deg, int* __restrict__ cnt,
                     int2* __restrict__ ell,
                     const float* __restrict__ X, _Float16* __restrict__ XB,
                     const float* __restrict__ Wx0, const float* __restrict__ Wx1,
                     const float* __restrict__ bx, const float* __restrict__ bh,
                     const float* __restrict__ wc, const float* __restrict__ bg,
                     _Float16* __restrict__ Wfrag, float* __restrict__ biasv,
                     float* __restrict__ wc2) {
    __shared__ _Float16 tile[4][512];
    int b = blockIdx.x;
    if (b < NB_BUILD) {
        const int stride = NB_BUILD * 256;
#pragma unroll 1
        for (int e = b * 256 + threadIdx.x; e < EE; e += stride) {
            int s = src[e], d = dst[e];
            float w = ew[e];
            atomicAdd(deg + s, w);              // fire-and-forget
            int pos = atomicAdd(cnt + d, 1);    // slot claim
            if (pos < ELLW) {
                int2 pr; pr.x = s; pr.y = __float_as_int(w);
                ell[(size_t)d * ELLW + pos] = pr;
            }
        }
    } else if (b < NB_BUILD + NB_XPOSE) {
        int wid = threadIdx.x >> 6, lane = threadIdx.x & 63;
        int n = (b - NB_BUILD) * 4 + wid;       // NN = 12500*4: no tail
        const float4* xp = (const float4*)(X + (size_t)n * 512 + lane * 8);
        float4 a = xp[0], c = xp[1];
        float v[8] = {a.x, a.y, a.z, a.w, c.x, c.y, c.z, c.w};
#pragma unroll
        for (int p = 0; p < PP; ++p)            // [p][f] layout, f = lane
            tile[wid][p * 64 + lane] = (_Float16)v[p];
        half8 vv = *(const half8*)&tile[wid][lane * 8];
        *(half8*)(XB + (size_t)n * 512 + lane * 8) = vv;
    } else if (b < NB_BUILD + NB_XPOSE + NB_WPACK) {
        // Wfrag pack: Wfrag[((ks*12+ct)*64+lane)*8+j] =
        //   W[k = ks*32+(lane>>4)*8+j][c = ct*16+(lane&15)]
        const int gmap[3] = {0, 2, 3};
        int t = (b - NB_BUILD - NB_XPOSE) * 256 + threadIdx.x;  // [0,24576)
        int j8 = t & 7;
        int lane = (t >> 3) & 63;
        int rem = t >> 9;           // [0,48)
        int ct = rem % 12;
        int ks = rem / 12;
        int k = ks * 32 + (lane >> 4) * 8 + j8;
        int gp = ct >> 2;
        int g = gmap[gp];
        int j64 = (ct & 3) * 16 + (lane & 15);
        float val = (k < 64) ? Wx0[((size_t)g * 64 + k) * 64 + j64]
                             : Wx1[((size_t)g * 64 + (k - 64)) * 64 + j64];
        Wfrag[t] = (_Float16)val;
    } else {
        // bias + wc2 (single block)
        const int gmap[3] = {0, 2, 3};
        int t = threadIdx.x;
        if (t < 192) {
            int gp = t / 64, j = t % 64;
            int g = gmap[gp];
            biasv[t] = bx[g * 64 + j] + bh[g * 64 + j] + bg[g * 64 + j];
        } else {
            int j = t - 192;                    // [0,64)
            wc2[j] = wc[2 * 64 + j];
        }
    }
}

__device__ __forceinline__ float fast_rcp(float x) { return __builtin_amdgcn_rcpf(x); }
__device__ __forceinline__ float sigmoidf_fast(float x) {
    return fast_rcp(1.f + __expf(-x));          // v_exp + v_rcp, no slow division
}
__device__ __forceinline__ float tanhf_fast(float x) {
    return 1.f - 2.f * fast_rcp(1.f + __expf(2.f * x));
}

// ---- K2: FUSED SpMM + MFMA GEMM + LSTM epilogue, R13: 4 waves/block --------
// R12 lesson: 2-wave shape starved the memory system (Occ 16.5%, 2.5 TB/s,
// ~85 outstanding gathers/CU vs split-spmm's ~384). Re-shape: 256 thr =
// 4 waves. Phase 1: wave w gathers rows [w*8, w*8+8) (serial chain halved).
// Phase 2: wave w owns column quarter w (Bf 12 half8 = 48 VGPR). LDS tile +
// XOR swizzle unchanged. ~16 waves/CU -> ~256 outstanding gathers/CU.
__global__ __launch_bounds__(256) void k_sg(const _Float16* __restrict__ XB,
                                            const int* __restrict__ cnt,
                                            const float* __restrict__ deg,
                                            const int2* __restrict__ ell,
                                            const _Float16* __restrict__ Wfrag,
                                            const float* __restrict__ biasv,
                                            const float* __restrict__ wc2,
                                            float* __restrict__ out) {
    __shared__ _Float16 Tl[32][512];            // 32 KB T-tile
    const int tid = threadIdx.x;
    const int w = tid >> 6;                     // wave id 0..3
    const int lane = tid & 63;
    const int n0 = blockIdx.x * 32;

    // ---- Phase 1: gather 8 rows per wave into LDS ----
#pragma unroll 1
    for (int r = 0; r < 8; ++r) {
        const int lr = w * 8 + r;               // local row
        const int n = n0 + lr;
        float acc[8] = {0.f, 0.f, 0.f, 0.f, 0.f, 0.f, 0.f, 0.f};
        float dn = 0.f;
        if (n < NN) {
            int cn = min(cnt[n], ELLW);
            float dgn = deg[n];
            dn = dgn > 0.f ? rsqrtf(fmaxf(dgn, 1e-12f)) : 0.f;
            if (cn > 0) {
                const int2* __restrict__ row = ell + (size_t)n * ELLW;
                int2 ed = row[min(lane, cn - 1)];
                float dgs = deg[ed.x];
                float dsr = dgs > 0.f ? rsqrtf(fmaxf(dgs, 1e-12f)) : 0.f;
                float wl = (lane < cn) ? dsr * __int_as_float(ed.y) : 0.f;
                int wli = __float_as_int(wl);
                for (int base = 0; base < cn; base += 16) {
                    half8 rg[16];
                    float wk[16];
#pragma unroll
                    for (int u = 0; u < 16; ++u) {
                        int srck = __builtin_amdgcn_readlane(ed.x, base + u); // SGPR
                        wk[u] = __int_as_float(__builtin_amdgcn_readlane(wli, base + u));
                        rg[u] = *((const half8*)(XB + (size_t)srck * 512) + lane);
                    }
#pragma unroll
                    for (int u = 0; u < 16; ++u) {
#pragma unroll
                        for (int j = 0; j < 8; ++j) acc[j] += wk[u] * (float)rg[u][j];
                    }
                }
            }
        }
        half8 st;
#pragma unroll
        for (int j = 0; j < 8; ++j) st[j] = (_Float16)(-dn * acc[j]);
        ((half8*)&Tl[lr][0])[lane ^ (lr & 7)] = st;   // swizzled store
    }
    __syncthreads();

    // ---- Phase 2: GEMM + LSTM epilogue; wave w = column quarter w ----
    const half8* __restrict__ Wg8 = (const half8*)Wfrag;
    const int jj = lane & 15, quad = lane >> 4;

    half8 Bf[3][4];                             // [gate i/c/o][ks]
#pragma unroll
    for (int gp = 0; gp < 3; ++gp)
#pragma unroll
        for (int ks = 0; ks < 4; ++ks)
            Bf[gp][ks] = Wg8[(ks * 12 + gp * 4 + w) * 64 + lane];

    const int jcol = w * 16 + jj;
    const float bi = biasv[jcol];
    const float bc = biasv[64 + jcol];
    const float bo = biasv[128 + jcol];
    const float wcv = wc2[jcol];

    const _Float16* __restrict__ x0 = XB + (size_t)(n0 + jj) * 512;
    const _Float16* __restrict__ x1 = XB + (size_t)(n0 + 16 + jj) * 512;
    const int sw0 = jj & 7;                     // swizzle key rows jj and 16+jj

    floatx4 outacc[2];
    outacc[0] = (floatx4){0.f, 0.f, 0.f, 0.f};
    outacc[1] = (floatx4){0.f, 0.f, 0.f, 0.f};

#pragma unroll 1
    for (int p = 0; p < PP; ++p) {
        const int o = p * 64 + quad * 8;
        const int c8 = p * 8 + quad;            // col8 of the fragment
        half8 a00 = *(const half8*)(x0 + o);
        half8 a01 = *(const half8*)(x0 + o + 32);
        half8 a02 = ((const half8*)&Tl[jj][0])[c8 ^ sw0];
        half8 a03 = ((const half8*)&Tl[jj][0])[(c8 + 4) ^ sw0];
        half8 a10 = *(const half8*)(x1 + o);
        half8 a11 = *(const half8*)(x1 + o + 32);
        half8 a12 = ((const half8*)&Tl[16 + jj][0])[c8 ^ sw0];
        half8 a13 = ((const half8*)&Tl[16 + jj][0])[(c8 + 4) ^ sw0];
        floatx4 ai0 = {0.f,0.f,0.f,0.f}, ac0 = {0.f,0.f,0.f,0.f}, ao0 = {0.f,0.f,0.f,0.f};
        floatx4 ai1 = {0.f,0.f,0.f,0.f}, ac1 = {0.f,0.f,0.f,0.f}, ao1 = {0.f,0.f,0.f,0.f};
#pragma unroll
        for (int ks = 0; ks < 4; ++ks) {
            half8 a0 = (ks == 0) ? a00 : (ks == 1) ? a01 : (ks == 2) ? a02 : a03;
            half8 a1 = (ks == 0) ? a10 : (ks == 1) ? a11 : (ks == 2) ? a12 : a13;
            ai0 = __builtin_amdgcn_mfma_f32_16x16x32_f16(a0, Bf[0][ks], ai0, 0, 0, 0);
            ai1 = __builtin_amdgcn_mfma_f32_16x16x32_f16(a1, Bf[0][ks], ai1, 0, 0, 0);
            ac0 = __builtin_amdgcn_mfma_f32_16x16x32_f16(a0, Bf[1][ks], ac0, 0, 0, 0);
            ac1 = __builtin_amdgcn_mfma_f32_16x16x32_f16(a1, Bf[1][ks], ac1, 0, 0, 0);
            ao0 = __builtin_amdgcn_mfma_f32_16x16x32_f16(a0, Bf[2][ks], ao0, 0, 0, 0);
            ao1 = __builtin_amdgcn_mfma_f32_16x16x32_f16(a1, Bf[2][ks], ao1, 0, 0, 0);
        }
        // fused epilogue: I=sig(ai); T=tanh(ac); Cn=I*T; O=sig(ao+wc2*Cn)
#pragma unroll
        for (int rr = 0; rr < 4; ++rr) {
            float I0 = sigmoidf_fast(ai0[rr] + bi);
            float T0 = tanhf_fast(ac0[rr] + bc);
            float Cn0 = I0 * T0;
            float O0 = sigmoidf_fast(ao0[rr] + bo + wcv * Cn0);
            outacc[0][rr] += O0 * tanhf_fast(Cn0);
            float I1 = sigmoidf_fast(ai1[rr] + bi);
            float T1 = tanhf_fast(ac1[rr] + bc);
            float Cn1 = I1 * T1;
            float O1 = sigmoidf_fast(ao1[rr] + bo + wcv * Cn1);
            outacc[1][rr] += O1 * tanhf_fast(Cn1);
        }
    }
    // store: row n = n0 + r*16 + quad*4 + rr, col = w*16 + jj
#pragma unroll
    for (int r = 0; r < 2; ++r)
#pragma unroll
        for (int rr = 0; rr < 4; ++rr) {
            int n = n0 + r * 16 + quad * 4 + rr;
            if (n < NN) out[(size_t)n * 64 + jcol] = outacc[r][rr];
        }
}

extern "C" void kernel_launch(void* const* d_in, const int* in_sizes, int n_in,
                              void* d_out, int out_size, void* d_ws, size_t ws_size,
                              hipStream_t stream) {
    const float* X   = (const float*)d_in[0];
    const int*   ei  = (const int*)d_in[1];
    const float* ew  = (const float*)d_in[2];
    const float* Wx0 = (const float*)d_in[3];
    const float* Wx1 = (const float*)d_in[4];
    const float* bx  = (const float*)d_in[5];
    // d_in[6], d_in[7] (Wh0, Wh1) are dead: H=0
    const float* bh  = (const float*)d_in[8];
    const float* wc  = (const float*)d_in[9];
    const float* bg  = (const float*)d_in[10];
    float* out = (float*)d_out;

    const int* src = ei;
    const int* dst = ei + EE;

    char* ws = (char*)d_ws;
    float* deg     = (float*)(ws + OFF_DEG);
    int*   cnt     = (int*)(ws + OFF_CNT);
    int2*  ell     = (int2*)(ws + OFF_ELL);
    float* biasv   = (float*)(ws + OFF_BIAS);
    float* wc2     = (float*)(ws + OFF_WC2);
    _Float16* Wfrag = (_Float16*)(ws + OFF_WFRG);
    _Float16* XB    = (_Float16*)(ws + OFF_XB);

    // zero deg + cnt (contiguous region at front of ws)
    hipMemsetAsync(ws, 0, OFF_END0, stream);

    // fused: build + xpose + Wfrag pack + bias/wc2 (block-specialized)
    k_bx<<<NB_BUILD + NB_XPOSE + NB_WPACK + 1, 256, 0, stream>>>(
        src, dst, ew, deg, cnt, ell, X, XB,
        Wx0, Wx1, bx, bh, wc, bg, Wfrag, biasv, wc2);
    // fused SpMM + GEMM + epilogue (4 waves/block)
    k_sg<<<NPAD / 32, 256, 0, stream>>>(XB, cnt, deg, ell, Wfrag, biasv, wc2, out);
}